// Round 2
// baseline (61.261 us; speedup 1.0000x reference)
//
#include <hip/hip_runtime.h>
#include <math.h>

// SpikeMLP: 2-layer spiking MLP, batch=128, in=800, hid=128, out=10.
//
// Trajectory: R3 66us -> R7 62.1us (2-kernel, closed-form crossing) ->
// R10 61.2us single-kernel per-batch fusion (layer 2 block-local via
// __syncthreads; removed d_ws round-trip + 2nd dispatch) ->
// R11 THIS: kill the mk[] LDS array. Theory: kernel is LDS-issue-bound:
// 800 ds_read_b128/CU x 12cyc = 9600 cyc (~4us) vs VALU 1600 cyc. The
// mask is recomputable from raw x in ~3 VALU ops/elem (idle pipe).
// Single xs[] array -> 400 LDS instr/CU (~2us), VALU ~4000cyc/SIMD
// (~1.7us, overlapped). Predicted kernel ~4us -> ~2.2us.
//
// Budget: ~40us harness ws-poison fill (256MB @ 6.7TB/s, untouchable) +
// ~10us other harness reset nodes/gaps + ~11us ours (R10).
//
// Layer-1 math (verified R3-R10): for t>=256 (the only finite-threshold
// steps) every finite ti < 1.0 <= t*DT, so mem(t) = t*DT*S - A with
// S=sum(W1[n,i]), A=sum(ti*W1[n,i]) over finite ti. mem(511)>0 gates
// spiking; first crossing of mem(t) > (511-t)*DT is closed-form:
// t > (A+511*DT)/(DT*(S+1)) for S+1>0, else t=256.
// Layer-2: v(t) = t*S2 - A2 linear (no relu) -> endpoint guard, faithful
// per-step loop only if v can approach 20. "No spike" sentinel = 1e30f
// (bf16-finite; harness compares in bf16 -> FLT_MAX/inf gives nan-fail).

#define DT (1.0f / 256.0f)
#define NSTEP 256
#define TSTEPS 512
#define IN_DIM 800
#define HID 128
#define OUT_DIM 10
#define NOSPIKE 1e30f

// ---------------- fused kernel: one block per batch row -------------------
// 128 blocks x 1024 threads. Layer 1: neuron n = tid>>3, slice s = tid&7,
// lane covers i = k*32 + s*4 (+3), k = 0..24 (25*32 = 800 exact, no tail).
// Layer 2: first 10 waves, o = tid>>6, j = tid&63; hs read from LDS.
__global__ __launch_bounds__(1024) void spike_fused(
    const float* __restrict__ x,    // [128, 800]
    const float* __restrict__ W1,   // [128, 800]
    const float* __restrict__ W2,   // [10, 128]
    float* __restrict__ out)        // [128, 10]
{
    const int b   = blockIdx.x;
    const int tid = threadIdx.x;
    const int n   = tid >> 3;              // hidden neuron 0..127
    const int s   = tid & 7;               // slice 0..7

    __shared__ __align__(16) float xs[IN_DIM];   // raw x row (1.0 = excluded)
    __shared__ float hs_sh[HID];                 // hidden spike times

    // Preload W2 fragment into registers for layer 2 (hides L2 latency
    // under layer-1 compute; only first 640 threads participate later).
    float w2a = 0.0f, w2b = 0.0f;
    if (tid < 640) {
        const int o = tid >> 6;
        const int j = tid & 63;
        const float* w2 = W2 + (size_t)o * HID;
        w2a = w2[j];
        w2b = w2[j + 64];
    }

    // stage x row into LDS (coalesced; one element per thread, 800 < 1024)
    const float* xr = x + (size_t)b * IN_DIM;
    if (tid < IN_DIM) {
        xs[tid] = xr[tid];
    }
    __syncthreads();

    // ---- layer 1: S = sum W1[n,i]*m, A = sum W1[n,i]*ti*m ----
    // mask m computed inline from raw xi (cmp+cndmask, VALU pipe is idle)
    const float* wr = W1 + (size_t)n * IN_DIM;
    float S = 0.0f;
    float A = 0.0f;
#pragma unroll
    for (int k = 0; k < 25; ++k) {                 // 25 x 32 = 800 elems
        const int i = k * 32 + s * 4;
        float4 wv = *(const float4*)(wr + i);
        float4 xv = *(const float4*)(&xs[i]);
        float m0 = (xv.x != 1.0f) ? 1.0f : 0.0f;  float v0 = (xv.x != 1.0f) ? xv.x : 0.0f;
        float m1 = (xv.y != 1.0f) ? 1.0f : 0.0f;  float v1 = (xv.y != 1.0f) ? xv.y : 0.0f;
        float m2 = (xv.z != 1.0f) ? 1.0f : 0.0f;  float v2 = (xv.z != 1.0f) ? xv.z : 0.0f;
        float m3 = (xv.w != 1.0f) ? 1.0f : 0.0f;  float v3 = (xv.w != 1.0f) ? xv.w : 0.0f;
        S = fmaf(m0, wv.x, S);  A = fmaf(v0, wv.x, A);
        S = fmaf(m1, wv.y, S);  A = fmaf(v1, wv.y, A);
        S = fmaf(m2, wv.z, S);  A = fmaf(v2, wv.z, A);
        S = fmaf(m3, wv.w, S);  A = fmaf(v3, wv.w, A);
    }
    // reduce across the 8 slices (contiguous lanes in the wave)
    S += __shfl_xor(S, 1);  A += __shfl_xor(A, 1);
    S += __shfl_xor(S, 2);  A += __shfl_xor(A, 2);
    S += __shfl_xor(S, 4);  A += __shfl_xor(A, 4);

    if (s == 0) {
        // first t in [256,511] with t*DT*S - A > (511-t)*DT, given
        // mem(511) > 0; closed form: t > (A + 511*DT) / (DT*(S+1)).
        float h;
        float mem_last = fmaf(511.0f * DT, S, -A);
        if (!(mem_last > 0.0f)) {
            h = 1.0f;                        // no spike -> sentinel 1.0
        } else {
            float Sp = S + 1.0f;
            int tf;
            if (!(Sp > 0.0f)) {
                tf = NSTEP;                  // lhs-rhs decreasing -> first step
            } else {
                float X = (A + 511.0f * DT) / (DT * Sp);
                tf = (int)floorf(X) + 1;     // smallest integer t with t > X
                if (tf < NSTEP)      tf = NSTEP;
                if (tf > TSTEPS - 1) tf = TSTEPS - 1;
            }
            h = (float)tf * DT - 1.0f;       // exact in fp32
        }
        hs_sh[n] = h;
    }
    __syncthreads();

    // ---- layer 2: first 10 waves, one output neuron per wave ----
    if (tid < 640) {
        const int j = tid & 63;

        float hi0 = hs_sh[j];
        float hi1 = hs_sh[j + 64];
        float m0  = (hi0 != 1.0f) ? 1.0f : 0.0f;  // h==1 -> INF -> excluded
        float m1  = (hi1 != 1.0f) ? 1.0f : 0.0f;

        float S2 = 0.0f, A2 = 0.0f;
        S2 = fmaf(m0, w2a, S2);   A2 = fmaf(m0 * hi0, w2a, A2);
        S2 = fmaf(m1, w2b, S2);   A2 = fmaf(m1 * hi1, w2b, A2);

#pragma unroll
        for (int msk = 1; msk < 64; msk <<= 1) {
            S2 += __shfl_xor(S2, msk);
            A2 += __shfl_xor(A2, msk);
        }
        if (j == 0) {
            const int o = tid >> 6;
            // v(t) = t*S2 - A2, t = 1 + k*DT, k in [0,1024): linear ->
            // endpoint guard; faithful loop only if near the 20.0 threshold.
            float res = NOSPIKE;
            float v_lo = fmaf(1.0f,                S2, -A2);
            float v_hi = fmaf(1.0f + 1023.0f * DT, S2, -A2);
            if (fmaxf(v_lo, v_hi) > 19.999f) {
                for (int k = 0; k < 1024; ++k) {
                    float t = fmaf((float)k, DT, 1.0f);   // exact fp32
                    float v = fmaf(t, S2, -A2);
                    if (v > 20.0f) { res = t; break; }
                }
            }
            out[b * OUT_DIM + o] = res;
        }
    }
}

extern "C" void kernel_launch(void* const* d_in, const int* in_sizes, int n_in,
                              void* d_out, int out_size, void* d_ws, size_t ws_size,
                              hipStream_t stream) {
    const float* x  = (const float*)d_in[0];   // (128, 800)
    const float* W1 = (const float*)d_in[1];   // (128, 800)
    const float* W2 = (const float*)d_in[2];   // (10, 128)
    float* out = (float*)d_out;                // (128, 10)
    (void)d_ws; (void)ws_size;

    spike_fused<<<128, 1024, 0, stream>>>(x, W1, W2, out);
}